// Round 1
// baseline (597.193 us; speedup 1.0000x reference)
//
#include <hip/hip_runtime.h>

// Problem constants
#define S_   1024
#define B_   8
#define E_   512
#define H_   8
#define QHD_ 32
#define PD_  4
#define F_   544     // (32+32+4)*8
#define M_   8192    // S_*B_

typedef __attribute__((ext_vector_type(8))) short bf16x8;
typedef __attribute__((ext_vector_type(4))) float f32x4;

static __device__ __forceinline__ unsigned short f2b(float f) {
  unsigned int u = __float_as_uint(f);
  u = (u + 0x7fffu + ((u >> 16) & 1u)) >> 16;   // RNE
  return (unsigned short)u;
}
static __device__ __forceinline__ float b2f(unsigned short u) {
  return __uint_as_float(((unsigned int)u) << 16);
}

// workspace byte offsets
#define OFF_QB   (size_t)(0)           // 4 MB bf16 [b][h][t][32]
#define OFF_KB   (size_t)(4u  << 20)   // 4 MB bf16 [b][h][s][32]
#define OFF_PF   (size_t)(8u  << 20)   // 1 MB f32  [b][h][t][4]
#define OFF_XHI  (size_t)(9u  << 20)   // 8 MB bf16 [m][e]
#define OFF_XLO  (size_t)(17u << 20)   // 8 MB
#define OFF_WHI  (size_t)(25u << 20)   // 0.54 MB bf16 [f][e]
#define OFF_WLO  (size_t)(26u << 20)
#define OFF_POS  (size_t)(27u << 20)   // 8 MB bf16 [t][s][4]

#define NX4 (M_ * E_ / 4)           // 1048576 float4s
#define NW4 (F_ * E_ / 4)           // 69632
#define NP4 (S_ * S_ * PD_ / 4)     // 1048576

// ---------------------------------------------------------------------------
// Kernel 1: fp32 -> bf16 conversions. x,W split hi/lo (split-bf16 precision),
// pos_emb plain bf16.
// ---------------------------------------------------------------------------
__global__ __launch_bounds__(256) void cvt_kernel(
    const float* __restrict__ x, const float* __restrict__ pos,
    const float* __restrict__ W,
    unsigned short* __restrict__ Xhi, unsigned short* __restrict__ Xlo,
    unsigned short* __restrict__ Whi, unsigned short* __restrict__ Wlo,
    unsigned short* __restrict__ PosB) {
  int i = blockIdx.x * 256 + threadIdx.x;
  if (i < NX4) {
    float4 v = reinterpret_cast<const float4*>(x)[i];
    ushort4 h, l;
    h.x = f2b(v.x); l.x = f2b(v.x - b2f(h.x));
    h.y = f2b(v.y); l.y = f2b(v.y - b2f(h.y));
    h.z = f2b(v.z); l.z = f2b(v.z - b2f(h.z));
    h.w = f2b(v.w); l.w = f2b(v.w - b2f(h.w));
    reinterpret_cast<ushort4*>(Xhi)[i] = h;
    reinterpret_cast<ushort4*>(Xlo)[i] = l;
    return;
  }
  i -= NX4;
  if (i < NW4) {
    float4 v = reinterpret_cast<const float4*>(W)[i];
    ushort4 h, l;
    h.x = f2b(v.x); l.x = f2b(v.x - b2f(h.x));
    h.y = f2b(v.y); l.y = f2b(v.y - b2f(h.y));
    h.z = f2b(v.z); l.z = f2b(v.z - b2f(h.z));
    h.w = f2b(v.w); l.w = f2b(v.w - b2f(h.w));
    reinterpret_cast<ushort4*>(Whi)[i] = h;
    reinterpret_cast<ushort4*>(Wlo)[i] = l;
    return;
  }
  i -= NW4;
  if (i < NP4) {
    float4 v = reinterpret_cast<const float4*>(pos)[i];
    ushort4 h;
    h.x = f2b(v.x); h.y = f2b(v.y); h.z = f2b(v.z); h.w = f2b(v.w);
    reinterpret_cast<ushort4*>(PosB)[i] = h;
  }
}

// ---------------------------------------------------------------------------
// Kernel 2: projection GEMM  xp[m,f] = sum_e x[m,e]*W[f,e] + b[f]
// m = s*8+b.  Split-bf16: acc += ah*bh + ah*bl + al*bh.
// Emits Q/K bf16 in [b][h][t][32], P fp32 [b][h][t][4].
// Workgroup: 4 waves, tile 64(M)x64(N); wave = 16(M)x64(N).
// ---------------------------------------------------------------------------
__global__ __launch_bounds__(256, 4) void proj_gemm(
    const unsigned short* __restrict__ Xhi, const unsigned short* __restrict__ Xlo,
    const unsigned short* __restrict__ Whi, const unsigned short* __restrict__ Wlo,
    const float* __restrict__ bias,
    unsigned short* __restrict__ Qb, unsigned short* __restrict__ Kb,
    float* __restrict__ Pf) {
  const int wid = threadIdx.x >> 6;
  const int l   = threadIdx.x & 63;
  const int g   = l >> 4, c = l & 15;
  const int wgM = blockIdx.x / 9, wgN = blockIdx.x % 9;
  const int mbase = wgM * 64 + wid * 16;
  const int nbase = wgN * 64;

  f32x4 acc[4] = {};
#pragma unroll 4
  for (int ks = 0; ks < 16; ++ks) {
    const int e = ks * 32 + 8 * g;
    bf16x8 ah = *reinterpret_cast<const bf16x8*>(Xhi + (mbase + c) * E_ + e);
    bf16x8 al = *reinterpret_cast<const bf16x8*>(Xlo + (mbase + c) * E_ + e);
#pragma unroll
    for (int j = 0; j < 4; ++j) {
      int f = nbase + j * 16 + c;
      if (f > F_ - 1) f = F_ - 1;           // clamp load, store is guarded
      bf16x8 bh = *reinterpret_cast<const bf16x8*>(Whi + f * E_ + e);
      bf16x8 bl = *reinterpret_cast<const bf16x8*>(Wlo + f * E_ + e);
      acc[j] = __builtin_amdgcn_mfma_f32_16x16x32_bf16(ah, bh, acc[j], 0, 0, 0);
      acc[j] = __builtin_amdgcn_mfma_f32_16x16x32_bf16(ah, bl, acc[j], 0, 0, 0);
      acc[j] = __builtin_amdgcn_mfma_f32_16x16x32_bf16(al, bh, acc[j], 0, 0, 0);
    }
  }
  // epilogue: C layout col=c (f-dim), row=4*g+r (m-dim)
#pragma unroll
  for (int j = 0; j < 4; ++j) {
    const int f = nbase + j * 16 + c;
    if (f >= F_) continue;
    const float bv = bias[f];
#pragma unroll
    for (int r = 0; r < 4; ++r) {
      const int m = mbase + 4 * g + r;
      const int s = m >> 3, b = m & 7;
      const float val = acc[j][r] + bv;
      if (f < 256) {
        const int h = f >> 5, d = f & 31;
        Qb[(((b * 8 + h) * S_) + s) * 32 + d] = f2b(val);
      } else if (f < 512) {
        const int f2 = f - 256, h = f2 >> 5, d = f2 & 31;
        Kb[(((b * 8 + h) * S_) + s) * 32 + d] = f2b(val);
      } else {
        const int f2 = f - 512, h = f2 >> 2, d = f2 & 3;
        Pf[(((b * 8 + h) * S_) + s) * 4 + d] = val;
      }
    }
  }
}

// ---------------------------------------------------------------------------
// Kernel 3: fused scores + softmax.
// Workgroup = (h, b, t16-block of 16 rows); wave w covers s in [w*256, w*256+256).
// Scores register-resident (16 tiles x f32x4). K frags loaded global->reg.
// ---------------------------------------------------------------------------
__global__ __launch_bounds__(256, 2) void attn_kernel(
    const unsigned short* __restrict__ Qb, const unsigned short* __restrict__ Kb,
    const float* __restrict__ Pf, const unsigned short* __restrict__ PosB,
    const float* __restrict__ Off, float* __restrict__ Out) {
  __shared__ float redm[4][16];
  __shared__ float reds[4][16];

  const int wid = threadIdx.x >> 6;
  const int l   = threadIdx.x & 63;
  const int g   = l >> 4, c = l & 15;

  // XCD-aware swizzle: all 64 (h,b) workgroups of a t-block on one XCD
  const int raw = blockIdx.x;
  const int wg  = (raw & 7) * 512 + (raw >> 3);
  const int h   = wg & 7;
  const int b   = (wg >> 3) & 7;
  const int t16 = wg >> 6;
  const int tbase = t16 * 16;
  const int sbase = wid * 256;
  const int bh_in  = b * 8 + h;
  const int bh_out = h * 8 + b;

  // Q fragment: A[m=c][k=8g+j]
  const bf16x8 qf =
      *reinterpret_cast<const bf16x8*>(Qb + (size_t)(bh_in * S_ + tbase + c) * 32 + 8 * g);
  // P rows for this lane: t = tbase + 4g + r
  float4 pv[4];
#pragma unroll
  for (int r = 0; r < 4; ++r)
    pv[r] = *reinterpret_cast<const float4*>(Pf + (size_t)(bh_in * S_ + tbase + 4 * g + r) * 4);

  f32x4 sc[16];
  {
    bf16x8 kf[16];
#pragma unroll
    for (int i = 0; i < 16; ++i)
      kf[i] = *reinterpret_cast<const bf16x8*>(
          Kb + (size_t)(bh_in * S_ + sbase + i * 16 + c) * 32 + 8 * g);
#pragma unroll
    for (int i = 0; i < 16; ++i) {
      f32x4 z = {};
      sc[i] = __builtin_amdgcn_mfma_f32_16x16x32_bf16(qf, kf[i], z, 0, 0, 0);
    }
  }

  // add pos-scores + attn_offset
#pragma unroll
  for (int i = 0; i < 16; ++i) {
    const int s = sbase + i * 16 + c;
#pragma unroll
    for (int r = 0; r < 4; ++r) {
      const int t = tbase + 4 * g + r;
      const ushort4 pb =
          *reinterpret_cast<const ushort4*>(PosB + ((size_t)t * S_ + s) * 4);
      const float off = Off[((size_t)b * S_ + t) * S_ + s];
      const float d0 = b2f(pb.x) * pv[r].x + b2f(pb.y) * pv[r].y +
                       b2f(pb.z) * pv[r].z + b2f(pb.w) * pv[r].w;
      sc[i][r] += off + d0;
    }
  }

  // row max (16 rows per workgroup; lane group g owns rows 4g..4g+3)
  float rm[4];
#pragma unroll
  for (int r = 0; r < 4; ++r) rm[r] = sc[0][r];
#pragma unroll
  for (int i = 1; i < 16; ++i)
#pragma unroll
    for (int r = 0; r < 4; ++r) rm[r] = fmaxf(rm[r], sc[i][r]);
#pragma unroll
  for (int mask = 1; mask <= 8; mask <<= 1)
#pragma unroll
    for (int r = 0; r < 4; ++r) rm[r] = fmaxf(rm[r], __shfl_xor(rm[r], mask));
  if (c == 0) {
#pragma unroll
    for (int r = 0; r < 4; ++r) redm[wid][4 * g + r] = rm[r];
  }
  __syncthreads();
  float M[4];
#pragma unroll
  for (int r = 0; r < 4; ++r) {
    const int row = 4 * g + r;
    M[r] = fmaxf(fmaxf(redm[0][row], redm[1][row]),
                 fmaxf(redm[2][row], redm[3][row]));
  }

  // exp + row sum
  float sm[4] = {0.f, 0.f, 0.f, 0.f};
#pragma unroll
  for (int i = 0; i < 16; ++i)
#pragma unroll
    for (int r = 0; r < 4; ++r) {
      const float e = __expf(sc[i][r] - M[r]);
      sc[i][r] = e;
      sm[r] += e;
    }
#pragma unroll
  for (int mask = 1; mask <= 8; mask <<= 1)
#pragma unroll
    for (int r = 0; r < 4; ++r) sm[r] += __shfl_xor(sm[r], mask);
  if (c == 0) {
#pragma unroll
    for (int r = 0; r < 4; ++r) reds[wid][4 * g + r] = sm[r];
  }
  __syncthreads();
  float inv[4];
#pragma unroll
  for (int r = 0; r < 4; ++r) {
    const int row = 4 * g + r;
    inv[r] = 1.0f / (reds[0][row] + reds[1][row] + reds[2][row] + reds[3][row]);
  }

  // normalized store: out[h][b][t][s]
  const size_t obase = (size_t)bh_out * (S_ * S_);
#pragma unroll
  for (int i = 0; i < 16; ++i) {
    const int s = sbase + i * 16 + c;
#pragma unroll
    for (int r = 0; r < 4; ++r) {
      const int t = tbase + 4 * g + r;
      Out[obase + (size_t)t * S_ + s] = sc[i][r] * inv[r];
    }
  }
}

// ---------------------------------------------------------------------------
extern "C" void kernel_launch(void* const* d_in, const int* in_sizes, int n_in,
                              void* d_out, int out_size, void* d_ws, size_t ws_size,
                              hipStream_t stream) {
  const float* x    = (const float*)d_in[0];
  const float* pos  = (const float*)d_in[1];
  const float* off  = (const float*)d_in[2];
  const float* W    = (const float*)d_in[3];
  const float* bias = (const float*)d_in[4];
  float* out = (float*)d_out;
  char* ws = (char*)d_ws;

  unsigned short* Qb   = (unsigned short*)(ws + OFF_QB);
  unsigned short* Kb   = (unsigned short*)(ws + OFF_KB);
  float*          Pf   = (float*)(ws + OFF_PF);
  unsigned short* Xhi  = (unsigned short*)(ws + OFF_XHI);
  unsigned short* Xlo  = (unsigned short*)(ws + OFF_XLO);
  unsigned short* Whi  = (unsigned short*)(ws + OFF_WHI);
  unsigned short* Wlo  = (unsigned short*)(ws + OFF_WLO);
  unsigned short* PosB = (unsigned short*)(ws + OFF_POS);

  const int cvt_blocks = (NX4 + NW4 + NP4 + 255) / 256;   // 8464
  cvt_kernel<<<cvt_blocks, 256, 0, stream>>>(x, pos, W, Xhi, Xlo, Whi, Wlo, PosB);

  proj_gemm<<<(M_ / 64) * 9, 256, 0, stream>>>(Xhi, Xlo, Whi, Wlo, bias, Qb, Kb, Pf);

  attn_kernel<<<H_ * B_ * (S_ / 16), 256, 0, stream>>>(Qb, Kb, Pf, PosB, off, out);
}

// Round 2
// 477.009 us; speedup vs baseline: 1.2520x; 1.2520x over previous
//
#include <hip/hip_runtime.h>

// Problem constants
#define S_   1024
#define B_   8
#define E_   512
#define H_   8
#define QHD_ 32
#define PD_  4
#define F_   544     // (32+32+4)*8
#define M_   8192    // S_*B_

typedef __attribute__((ext_vector_type(8))) short bf16x8;
typedef __attribute__((ext_vector_type(4))) float f32x4;

static __device__ __forceinline__ unsigned short f2b(float f) {
  unsigned int u = __float_as_uint(f);
  u = (u + 0x7fffu + ((u >> 16) & 1u)) >> 16;   // RNE
  return (unsigned short)u;
}
static __device__ __forceinline__ float b2f(unsigned short u) {
  return __uint_as_float(((unsigned int)u) << 16);
}

// Exact truncation split: hi = trunc-bf16(v), lo = trunc-bf16(v - hi).
// |err| <= 2^-16 |v| -- well below the bf16-pair budget.
static __device__ __forceinline__ void split8(const float* p, bf16x8& hi, bf16x8& lo) {
  float4 a = *reinterpret_cast<const float4*>(p);
  float4 b = *reinterpret_cast<const float4*>(p + 4);
  float v[8] = {a.x, a.y, a.z, a.w, b.x, b.y, b.z, b.w};
#pragma unroll
  for (int k = 0; k < 8; ++k) {
    unsigned int u = __float_as_uint(v[k]);
    unsigned short hs = (unsigned short)(u >> 16);
    float hf = __uint_as_float(((unsigned int)hs) << 16);
    float lf = v[k] - hf;
    hi[k] = (short)hs;
    lo[k] = (short)(__float_as_uint(lf) >> 16);
  }
}

// workspace byte offsets
#define OFF_QB   (size_t)(0)           // 4 MB bf16 [b][h][t][32]
#define OFF_KB   (size_t)(4u  << 20)   // 4 MB bf16 [b][h][s][32]
#define OFF_PB   (size_t)(8u  << 20)   // 512 KB bf16 [b][h][t][4]
#define OFF_POS  (size_t)(9u  << 20)   // 8 MB bf16 [t][s][4]

#define NP4 (S_ * S_ * PD_ / 4)     // 1048576 float4s of pos

// ---------------------------------------------------------------------------
// Kernel 1: pos_emb fp32 -> bf16 (plain RNE)
// ---------------------------------------------------------------------------
__global__ __launch_bounds__(256) void cvt_pos(
    const float* __restrict__ pos, unsigned short* __restrict__ PosB) {
  int i = blockIdx.x * 256 + threadIdx.x;
  if (i >= NP4) return;
  float4 v = reinterpret_cast<const float4*>(pos)[i];
  ushort4 h;
  h.x = f2b(v.x); h.y = f2b(v.y); h.z = f2b(v.z); h.w = f2b(v.w);
  reinterpret_cast<ushort4*>(PosB)[i] = h;
}

// ---------------------------------------------------------------------------
// Kernel 2: projection GEMM  xp[m,f] = sum_e x[m,e]*W[f,e] + b[f]
// fp32 inputs, in-register hi/lo split, 3-term split-bf16 MFMA.
// Emits Q/K bf16 [b][h][t][32], P bf16 [b][h][t][4].
// Tile 64(M)x64(N), 4 waves. Grid 1152 = 8 XCD-groups x 144; each XCD owns a
// contiguous 1024-row x slice (x-slice 2MB + W 1.1MB fits its L2).
// ---------------------------------------------------------------------------
__global__ __launch_bounds__(256, 4) void proj_gemm(
    const float* __restrict__ x, const float* __restrict__ W,
    const float* __restrict__ bias,
    unsigned short* __restrict__ Qb, unsigned short* __restrict__ Kb,
    unsigned short* __restrict__ Pb) {
  const int wid = threadIdx.x >> 6;
  const int l   = threadIdx.x & 63;
  const int g   = l >> 4, c = l & 15;
  const int xcd = blockIdx.x & 7;
  const int k   = blockIdx.x >> 3;          // 0..143
  const int wgM = xcd * 16 + k / 9;
  const int wgN = k % 9;
  const int mbase = wgM * 64 + wid * 16;
  const int nbase = wgN * 64;

  f32x4 acc[4] = {};
#pragma unroll 4
  for (int ks = 0; ks < 16; ++ks) {
    const int e = ks * 32 + 8 * g;
    bf16x8 ah, al;
    split8(x + (size_t)(mbase + c) * E_ + e, ah, al);
#pragma unroll
    for (int j = 0; j < 4; ++j) {
      int f = nbase + j * 16 + c;
      if (f > F_ - 1) f = F_ - 1;           // clamp load, store is guarded
      bf16x8 bh, bl;
      split8(W + (size_t)f * E_ + e, bh, bl);
      acc[j] = __builtin_amdgcn_mfma_f32_16x16x32_bf16(ah, bh, acc[j], 0, 0, 0);
      acc[j] = __builtin_amdgcn_mfma_f32_16x16x32_bf16(ah, bl, acc[j], 0, 0, 0);
      acc[j] = __builtin_amdgcn_mfma_f32_16x16x32_bf16(al, bh, acc[j], 0, 0, 0);
    }
  }
  // epilogue: C layout col=c (f-dim), row=4*g+r (m-dim)
#pragma unroll
  for (int j = 0; j < 4; ++j) {
    const int f = nbase + j * 16 + c;
    if (f >= F_) continue;
    const float bv = bias[f];
#pragma unroll
    for (int r = 0; r < 4; ++r) {
      const int m = mbase + 4 * g + r;
      const int s = m >> 3, b = m & 7;
      const float val = acc[j][r] + bv;
      if (f < 256) {
        const int h = f >> 5, d = f & 31;
        Qb[(((b * 8 + h) * S_) + s) * 32 + d] = f2b(val);
      } else if (f < 512) {
        const int f2 = f - 256, h = f2 >> 5, d = f2 & 31;
        Kb[(((b * 8 + h) * S_) + s) * 32 + d] = f2b(val);
      } else {
        const int f2 = f - 512, h = f2 >> 2, d = f2 & 3;
        Pb[(((b * 8 + h) * S_) + s) * 4 + d] = f2b(val);
      }
    }
  }
}

// ---------------------------------------------------------------------------
// Kernel 3: fused scores + softmax.
// Workgroup = (h, b, t16): 512 threads, 8 waves; wave w covers s in
// [w*128, w*128+128) -> sc[8] register-resident tiles (32 acc regs).
// XCD swizzle: XCD x owns t16 in [x*8, x*8+8); within an XCD, launch order is
// b outer, t16 middle, h inner -> concurrent working set (K 512KB + off/pos
// ~0.4MB) stays L2-resident.
// ---------------------------------------------------------------------------
__global__ __launch_bounds__(512, 4) void attn_kernel(
    const unsigned short* __restrict__ Qb, const unsigned short* __restrict__ Kb,
    const unsigned short* __restrict__ Pb, const unsigned short* __restrict__ PosB,
    const float* __restrict__ Off, float* __restrict__ Out) {
  __shared__ float redm[8][16];
  __shared__ float reds[8][16];

  const int wid = threadIdx.x >> 6;
  const int l   = threadIdx.x & 63;
  const int g   = l >> 4, c = l & 15;

  const int n    = blockIdx.x;
  const int h    = (n >> 3) & 7;
  const int t16l = (n >> 6) & 7;
  const int b    = (n >> 9) & 7;
  const int t16  = (n & 7) * 8 + t16l;

  const int tbase = t16 * 16;
  const int sbase = wid * 128;
  const int bh_in  = b * 8 + h;
  const int bh_out = h * 8 + b;

  // Q fragment: A[m=c][k=8g+j]
  const bf16x8 qf =
      *reinterpret_cast<const bf16x8*>(Qb + (size_t)(bh_in * S_ + tbase + c) * 32 + 8 * g);
  // P rows for this lane: t = tbase + 4g + r  (bf16 -> 16 floats)
  float pv[4][4];
#pragma unroll
  for (int r = 0; r < 4; ++r) {
    const ushort4 pb =
        *reinterpret_cast<const ushort4*>(Pb + (size_t)(bh_in * S_ + tbase + 4 * g + r) * 4);
    pv[r][0] = b2f(pb.x); pv[r][1] = b2f(pb.y);
    pv[r][2] = b2f(pb.z); pv[r][3] = b2f(pb.w);
  }

  f32x4 sc[8];
  {
    bf16x8 kf[8];
#pragma unroll
    for (int i = 0; i < 8; ++i)
      kf[i] = *reinterpret_cast<const bf16x8*>(
          Kb + (size_t)(bh_in * S_ + sbase + i * 16 + c) * 32 + 8 * g);
#pragma unroll
    for (int i = 0; i < 8; ++i) {
      f32x4 z = {};
      sc[i] = __builtin_amdgcn_mfma_f32_16x16x32_bf16(qf, kf[i], z, 0, 0, 0);
    }
  }

  // add pos-scores + attn_offset
#pragma unroll
  for (int i = 0; i < 8; ++i) {
    const int s = sbase + i * 16 + c;
#pragma unroll
    for (int r = 0; r < 4; ++r) {
      const int t = tbase + 4 * g + r;
      const ushort4 pb =
          *reinterpret_cast<const ushort4*>(PosB + ((size_t)t * S_ + s) * 4);
      const float off = Off[((size_t)b * S_ + t) * S_ + s];
      const float d0 = b2f(pb.x) * pv[r][0] + b2f(pb.y) * pv[r][1] +
                       b2f(pb.z) * pv[r][2] + b2f(pb.w) * pv[r][3];
      sc[i][r] += off + d0;
    }
  }

  // row max (rows 4g..4g+3 within this 16-lane group)
  float rm[4];
#pragma unroll
  for (int r = 0; r < 4; ++r) rm[r] = sc[0][r];
#pragma unroll
  for (int i = 1; i < 8; ++i)
#pragma unroll
    for (int r = 0; r < 4; ++r) rm[r] = fmaxf(rm[r], sc[i][r]);
#pragma unroll
  for (int mask = 1; mask <= 8; mask <<= 1)
#pragma unroll
    for (int r = 0; r < 4; ++r) rm[r] = fmaxf(rm[r], __shfl_xor(rm[r], mask));
  if (c == 0) {
#pragma unroll
    for (int r = 0; r < 4; ++r) redm[wid][4 * g + r] = rm[r];
  }
  __syncthreads();
  float M[4];
#pragma unroll
  for (int r = 0; r < 4; ++r) {
    const int row = 4 * g + r;
    float m0 = fmaxf(fmaxf(redm[0][row], redm[1][row]),
                     fmaxf(redm[2][row], redm[3][row]));
    float m1 = fmaxf(fmaxf(redm[4][row], redm[5][row]),
                     fmaxf(redm[6][row], redm[7][row]));
    M[r] = fmaxf(m0, m1);
  }

  // exp + row sum
  float sm[4] = {0.f, 0.f, 0.f, 0.f};
#pragma unroll
  for (int i = 0; i < 8; ++i)
#pragma unroll
    for (int r = 0; r < 4; ++r) {
      const float e = __expf(sc[i][r] - M[r]);
      sc[i][r] = e;
      sm[r] += e;
    }
#pragma unroll
  for (int mask = 1; mask <= 8; mask <<= 1)
#pragma unroll
    for (int r = 0; r < 4; ++r) sm[r] += __shfl_xor(sm[r], mask);
  if (c == 0) {
#pragma unroll
    for (int r = 0; r < 4; ++r) reds[wid][4 * g + r] = sm[r];
  }
  __syncthreads();
  float inv[4];
#pragma unroll
  for (int r = 0; r < 4; ++r) {
    const int row = 4 * g + r;
    float s0 = (reds[0][row] + reds[1][row]) + (reds[2][row] + reds[3][row]);
    float s1 = (reds[4][row] + reds[5][row]) + (reds[6][row] + reds[7][row]);
    inv[r] = 1.0f / (s0 + s1);
  }

  // normalized store: out[h][b][t][s]
  const size_t obase = (size_t)bh_out * (S_ * S_);
#pragma unroll
  for (int i = 0; i < 8; ++i) {
    const int s = sbase + i * 16 + c;
#pragma unroll
    for (int r = 0; r < 4; ++r) {
      const int t = tbase + 4 * g + r;
      Out[obase + (size_t)t * S_ + s] = sc[i][r] * inv[r];
    }
  }
}

// ---------------------------------------------------------------------------
extern "C" void kernel_launch(void* const* d_in, const int* in_sizes, int n_in,
                              void* d_out, int out_size, void* d_ws, size_t ws_size,
                              hipStream_t stream) {
  const float* x    = (const float*)d_in[0];
  const float* pos  = (const float*)d_in[1];
  const float* off  = (const float*)d_in[2];
  const float* W    = (const float*)d_in[3];
  const float* bias = (const float*)d_in[4];
  float* out = (float*)d_out;
  char* ws = (char*)d_ws;

  unsigned short* Qb   = (unsigned short*)(ws + OFF_QB);
  unsigned short* Kb   = (unsigned short*)(ws + OFF_KB);
  unsigned short* Pb   = (unsigned short*)(ws + OFF_PB);
  unsigned short* PosB = (unsigned short*)(ws + OFF_POS);

  cvt_pos<<<(NP4 + 255) / 256, 256, 0, stream>>>(pos, PosB);

  proj_gemm<<<(M_ / 64) * 9, 256, 0, stream>>>(x, W, bias, Qb, Kb, Pb);

  attn_kernel<<<H_ * B_ * (S_ / 16), 512, 0, stream>>>(Qb, Kb, Pb, PosB, off, out);
}